// Round 12
// baseline (702.841 us; speedup 1.0000x reference)
//
#include <hip/hip_runtime.h>
#include <cmath>

// ---------------------------------------------------------------------------
// SwinV2-style window attention, f16-MFMA implementation.  Round 18.
//
// R17 (cooperative fused) produced absmax ~= max|ref|: the cooperative
// launch was silently rejected (phase bodies are verbatim R16 which
// passes).  R18 keeps the fusion but swaps grid.sync() for a SOFTWARE
// sense-reversing grid barrier (agent-scope __hip_atomic cnt/gen in d_ws,
// zeroed by captured hipMemsetAsync) and launches with plain <<<>>>.
// Co-residency of 1024 blocks is structural: launch_bounds(256,4) caps
// VGPR at 128, LDS 18.4KB -> 4 blocks/CU x 256 CU = 1024 exactly.
// Phase bodies verbatim R16: prep -> qkv -> attn -> proj.
// ---------------------------------------------------------------------------

typedef _Float16 half_t;
typedef __attribute__((ext_vector_type(2))) __fp16 fp16x2;
typedef __attribute__((ext_vector_type(4))) _Float16 half4;
typedef __attribute__((ext_vector_type(8))) _Float16 half8;
typedef __attribute__((ext_vector_type(2))) float float2v;
typedef __attribute__((ext_vector_type(4))) float float4v;
typedef __attribute__((ext_vector_type(4))) unsigned int uint4v;

static __device__ __forceinline__ float4v mfma16(half8 a, half8 b, float4v c) {
  return __builtin_amdgcn_mfma_f32_16x16x32_f16(a, b, c, 0, 0, 0);
}

struct FusedArgs {
  const float* x;
  const float* wsrc[8];
  const float* bsrc[8];
  const float* w1;
  const float* b1;
  const float* w2;
  const float* ls;
  half_t* wf;
  float* bws;
  float* tabd;
  half_t* qf;
  half_t* kf;
  half_t* vf;
  half_t* ao;
  float* out;
  unsigned* bar;  // [0]=cnt, [1]=gen (zeroed before launch)
};

// Sense-reversing grid barrier.  Read gen BEFORE registering arrival.
// ACQ_REL/ACQUIRE at agent scope emit the L2 wb/inv needed cross-XCD.
static __device__ __forceinline__ void grid_barrier(unsigned* cnt,
                                                    unsigned* gen,
                                                    unsigned nb) {
  __syncthreads();
  if (threadIdx.x == 0) {
    unsigned g =
        __hip_atomic_load(gen, __ATOMIC_RELAXED, __HIP_MEMORY_SCOPE_AGENT);
    unsigned prev = __hip_atomic_fetch_add(cnt, 1u, __ATOMIC_ACQ_REL,
                                           __HIP_MEMORY_SCOPE_AGENT);
    if (prev == nb - 1u) {
      __hip_atomic_store(cnt, 0u, __ATOMIC_RELAXED,
                         __HIP_MEMORY_SCOPE_AGENT);
      __hip_atomic_fetch_add(gen, 1u, __ATOMIC_ACQ_REL,
                             __HIP_MEMORY_SCOPE_AGENT);
    } else {
      while (__hip_atomic_load(gen, __ATOMIC_ACQUIRE,
                               __HIP_MEMORY_SCOPE_AGENT) == g)
        __builtin_amdgcn_s_sleep(8);
    }
  }
  __syncthreads();
}

// ---- attn-phase macros (verbatim R16) -------------------------------------
#define LOADK(kt)                                                           \
  {                                                                         \
    _Pragma("unroll") for (int nt = 0; nt < 4; nt++)                        \
        kfr[nt] = *(const half8*)(kbase + ((kt)*64 + nt * 16 + l) * 32 +    \
                                  quad * 8);                                \
  }

#define LOADV(kt)                                                           \
  {                                                                         \
    _Pragma("unroll") for (int ks = 0; ks < 2; ks++) {                      \
      vv0[ks] = *(const half8*)(vbase + l * 1024 + (kt)*64 + quad * 16 +    \
                                ks * 8);                                    \
      vv1[ks] = *(const half8*)(vbase + (16 + l) * 1024 + (kt)*64 +         \
                                quad * 16 + ks * 8);                        \
    }                                                                       \
  }

#define QK_PHASE(kt, S, SR)                                                 \
  {                                                                         \
    int rowb = (wv + 31 - 2 * (kt)) * 63 + cA + (S)*16;                     \
    _Pragma("unroll") for (int nt = 0; nt < 4; nt++) {                      \
      int base = rowb - (nt >> 1) * 63 - (nt & 1) * 16;                     \
      float2v p0 = sb2d[base];                                              \
      float2v p1 = sb2d[base - 2];                                          \
      float4v c;                                                            \
      c[0] = p0[1];                                                         \
      c[1] = p0[0];                                                         \
      c[2] = p1[1];                                                         \
      c[3] = p1[0];                                                         \
      SR[nt] = mfma16(kfr[nt], qfr[S], c);                                  \
    }                                                                       \
  }

#define EXP_PACK(S, SR)                                                     \
  {                                                                         \
    unsigned int w0[4], w1[4];                                              \
    _Pragma("unroll") for (int nt = 0; nt < 4; nt++) {                      \
      fp16x2 plo = __builtin_amdgcn_cvt_pkrtz(                              \
          __builtin_amdgcn_exp2f(SR[nt][0]),                                \
          __builtin_amdgcn_exp2f(SR[nt][1]));                               \
      fp16x2 phi = __builtin_amdgcn_cvt_pkrtz(                              \
          __builtin_amdgcn_exp2f(SR[nt][2]),                                \
          __builtin_amdgcn_exp2f(SR[nt][3]));                               \
      w0[nt] = __builtin_bit_cast(unsigned int, plo);                       \
      w1[nt] = __builtin_bit_cast(unsigned int, phi);                       \
    }                                                                       \
    uint4v u0 = {w0[0], w0[1], w0[2], w0[3]};                               \
    uint4v u1 = {w1[0], w1[1], w1[2], w1[3]};                               \
    pf##S[0] = __builtin_bit_cast(half8, u0);                               \
    pf##S[1] = __builtin_bit_cast(half8, u1);                               \
  }

#define PV_PHASE(S)                                                         \
  {                                                                         \
    _Pragma("unroll") for (int ks = 0; ks < 2; ks++) {                      \
      o0[S] = mfma16(pf##S[ks], vv0[ks], o0[S]);                            \
      o1[S] = mfma16(pf##S[ks], vv1[ks], o1[S]);                            \
      accl[S] = mfma16(pf##S[ks], ones, accl[S]);                           \
    }                                                                       \
  }

// ---------------------------------------------------------------------------
__global__ __launch_bounds__(256, 4) void fused_all(FusedArgs a) {
  __shared__ float4v smem_raw[1152];  // 18432 B arena, reused per phase
  int id = blockIdx.x;
  int t = threadIdx.x;

  // ======== phase 0: prep (blocks 0..127 W-frag, 128..143 bias MLP) ========
  if (id < 128) {
    int y = id >> 4, xx = id & 15;
    const float* src = nullptr;
    const float* bs = nullptr;
#pragma unroll
    for (int i = 0; i < 8; i++)
      if (i == y) { src = a.wsrc[i]; bs = a.bsrc[i]; }
    int flat = (xx * 256 + t) * 4;
    float4 w = *(const float4*)(src + flat);
    int j = flat >> 7, k = flat & 127;
    if (y < 6) {
      if (k == j)     w.x += 1.0f;
      if (k + 1 == j) w.y += 1.0f;
      if (k + 2 == j) w.z += 1.0f;
      if (k + 3 == j) w.w += 1.0f;
    }
    half4 h;
    h[0] = (half_t)w.x;
    h[1] = (half_t)w.y;
    h[2] = (half_t)w.z;
    h[3] = (half_t)w.w;
    int ng = j >> 4, l = j & 15, ks = k >> 5, quad = (k >> 3) & 3, o8 = k & 7;
    *(half4*)(a.wf + y * 16384 + ((ng * 4 + ks) * 64 + quad * 16 + l) * 8 +
              o8) = h;
    if (xx == 0 && t < 128) a.bws[y * 128 + t] = bs[t];
  } else if (id < 144) {
    float* smem = (float*)smem_raw;
    float* sw1 = smem;
    float* sb1 = smem + 256;
    float* sw2 = smem + 384;
    sw1[t] = a.w1[t];
    if (t < 128) sb1[t] = a.b1[t];
    for (int i = t; i < 1024; i += 256) sw2[i] = a.w2[i];
    __syncthreads();
    int p = (id - 128) * 256 + t;
    if (p < 3969) {
      int ph = p / 63, pw = p % 63;
      float t0 = (float)(ph - 31) * (3.2f / 31.0f);
      float t1 = (float)(pw - 31) * (3.2f / 31.0f);
      t0 = copysignf(1.0f - __expf(-fabsf(t0)), t0);
      t1 = copysignf(1.0f - __expf(-fabsf(t1)), t1);
      float acc[8];
#pragma unroll
      for (int hh = 0; hh < 8; hh++) acc[hh] = 0.0f;
      for (int j = 0; j < 128; j++) {
        float hj =
            fmaxf(0.0f, t0 * sw1[2 * j] + t1 * sw1[2 * j + 1] + sb1[j]);
#pragma unroll
        for (int hh = 0; hh < 8; hh++) acc[hh] += hj * sw2[hh * 128 + j];
      }
      const float L2E = 1.44269504f;
#pragma unroll
      for (int hh = 0; hh < 8; hh++) {
        float scale = __expf(fminf(a.ls[hh], 4.6051702f));
        float c14 = 14.0f - (scale + 16.0f) * L2E;
        float bias = 16.0f / (1.0f + __expf(-acc[hh]));
        float v = bias * L2E + c14;
        float* td = a.tabd + hh * 7940;  // float2[3970] per h
        td[p * 2 + 1] = v;
        td[p * 2 + 2] = v;
        if (p == 0) td[0] = 0.0f;
      }
    }
  }
  grid_barrier(a.bar, a.bar + 1, 1024u);

  // ======== phase 1: qkv (id -> bx 0..511, hf 0..1) ========================
  {
    half_t* tbuf = (half_t*)smem_raw;  // x-stage [128][36]; q/k [32][136]
    int bx = id & 511, hf = id >> 9;
    int lane = t & 63, wv = t >> 6, l = lane & 15, quad = lane >> 4;
    int rw = wv & 1, cw = wv >> 1;
    int m0 = bx * 32;
    int b = m0 >> 10, n0 = m0 & 1023;

    {
      const float* xb = a.x + ((size_t)b * 256 + hf * 128) * 1024 + n0;
      int ch = t >> 3, no = (t & 7) * 4;
#pragma unroll
      for (int p = 0; p < 4; p++) {
        float4 v = *(const float4*)(xb + (size_t)(p * 32 + ch) * 1024 + no);
        half4 h;
        h[0] = (half_t)v.x;
        h[1] = (half_t)v.y;
        h[2] = (half_t)v.z;
        h[3] = (half_t)v.w;
        *(half4*)(tbuf + (p * 32 + ch) * 36 + no) = h;
      }
    }
    __syncthreads();

    half8 afr[4];
#pragma unroll
    for (int ks = 0; ks < 4; ks++) {
      half8 aa;
#pragma unroll
      for (int j = 0; j < 8; j++)
        aa[j] = tbuf[(ks * 32 + quad * 8 + j) * 36 + rw * 16 + l];
      afr[ks] = aa;
    }
    __syncthreads();

    for (int op = 0; op < 3; op++) {
      int combo = op * 2 + hf;
      const half_t* wfb = a.wf + combo * 16384;
      float4v acc[4];
#pragma unroll
      for (int ngl = 0; ngl < 4; ngl++) {
        int ng = cw * 4 + ngl;
        float4v c = {0.f, 0.f, 0.f, 0.f};
#pragma unroll
        for (int ks = 0; ks < 4; ks++) {
          half8 bfrag =
              *(const half8*)(wfb + ((ng * 4 + ks) * 64 + lane) * 8);
          c = mfma16(afr[ks], bfrag, c);
        }
        acc[ngl] = c;
      }
#pragma unroll
      for (int ngl = 0; ngl < 4; ngl++) {
        float bb = a.bws[combo * 128 + (cw * 4 + ngl) * 16 + l];
#pragma unroll
        for (int r2 = 0; r2 < 4; r2++) acc[ngl][r2] += bb;
      }
      if (op < 2) {
#pragma unroll
        for (int hgl = 0; hgl < 2; hgl++) {
          float sc = 1.0f;
          if (op == 0)
            sc = __expf(fminf(a.ls[hf * 4 + cw * 2 + hgl], 4.6051702f)) *
                 1.44269504f;
#pragma unroll
          for (int r2 = 0; r2 < 4; r2++) {
            float ss = acc[2 * hgl][r2] * acc[2 * hgl][r2] +
                       acc[2 * hgl + 1][r2] * acc[2 * hgl + 1][r2];
            ss += __shfl_xor(ss, 1, 64);
            ss += __shfl_xor(ss, 2, 64);
            ss += __shfl_xor(ss, 4, 64);
            ss += __shfl_xor(ss, 8, 64);
            float rn = sc / fmaxf(sqrtf(ss), 1e-12f);
            acc[2 * hgl][r2] *= rn;
            acc[2 * hgl + 1][r2] *= rn;
          }
        }
#pragma unroll
        for (int ngl = 0; ngl < 4; ngl++)
#pragma unroll
          for (int r2 = 0; r2 < 4; r2++)
            tbuf[(rw * 16 + quad * 4 + r2) * 136 + (cw * 4 + ngl) * 16 + l] =
                (half_t)acc[ngl][r2];
        __syncthreads();
        half_t* dst = (op == 0) ? a.qf : a.kf;
#pragma unroll
        for (int i = 0; i < 2; i++) {
          int idx = t + 256 * i;
          int row = idx >> 4, colc = (idx & 15) * 8;
          half8 vv = *(const half8*)(tbuf + row * 136 + colc);
          int head = hf * 4 + (colc >> 5), d = colc & 31;
          *(half8*)(dst + (((size_t)b * 8 + head) * 1024 + n0 + row) * 32 +
                    d) = vv;
        }
        __syncthreads();
      } else {
#pragma unroll
        for (int ngl = 0; ngl < 4; ngl++) {
          int col = (cw * 4 + ngl) * 16 + l;
          half4 hv;
#pragma unroll
          for (int r2 = 0; r2 < 4; r2++) hv[r2] = (half_t)acc[ngl][r2];
          *(half4*)(tbuf + col * 36 + rw * 16 + quad * 4) = hv;
        }
        __syncthreads();
        int p64 = (n0 >> 5) & 1;
        int nb64 = n0 & ~63;
#pragma unroll
        for (int i = 0; i < 8; i++) {
          int idx = t + 256 * i;
          int col = idx >> 4, rp = idx & 15;
          unsigned int val =
              *(const unsigned int*)(tbuf + col * 36 + rp * 2);
          int head = hf * 4 + (col >> 5);
          int d = col & 31;
          int npos = nb64 + ((rp >> 1) & 3) * 16 + (rp & 1) * 8 + p64 * 4 +
                     ((rp >> 3) & 1) * 2;
          *(unsigned int*)((char*)a.vf +
                           (((((size_t)b * 8 + head) * 32 + d) * 1024) +
                            npos) * 2) = val;
        }
      }
    }
  }
  grid_barrier(a.bar, a.bar + 1, 1024u);

  // ======== phase 2: attn (verbatim R16) ===================================
  {
    float2v* sb2d = (float2v*)smem_raw;  // bias pairs, 17640 B
    int qo = id >> 7;
    int bh = id & 127;
    int h = bh & 7, b = bh >> 3;
    int lane = t & 63, wv = t >> 6, l = lane & 15, quad = lane >> 4;
    size_t bhs = (size_t)b * 8 + h;
    const half_t* kbase = a.kf + bhs * 1024 * 32;
    const half_t* vbase = a.vf + bhs * 32 * 1024;
    int row0 = qo * 128 + wv * 32;
    int cA = l + 31 - quad * 4;

    half8 kfr[4], vv0[2], vv1[2], qfr[2], pf0[2], pf1[2];
    LOADK(0);
    LOADV(0);
#pragma unroll
    for (int s = 0; s < 2; s++)
      qfr[s] = *(const half8*)(a.qf + (bhs * 1024 + row0 + s * 16 + l) * 32 +
                               quad * 8);

    {
      const float2v* td =
          (const float2v*)(a.tabd + (size_t)h * 7940) + qo * 252;
      for (int i = t; i < 2205; i += 256) sb2d[i] = td[i];
    }

    float4v o0[2], o1[2], accl[2];
#pragma unroll
    for (int s = 0; s < 2; s++) {
      o0[s] = (float4v){0.f, 0.f, 0.f, 0.f};
      o1[s] = (float4v){0.f, 0.f, 0.f, 0.f};
      accl[s] = (float4v){0.f, 0.f, 0.f, 0.f};
    }
    half8 ones;
#pragma unroll
    for (int j = 0; j < 8; j++) ones[j] = (half_t)1.0f;

    __syncthreads();

#pragma unroll
    for (int kt = 0; kt < 16; ++kt) {
      float4v sres[4];
      QK_PHASE(kt, 0, sres);
      EXP_PACK(0, sres);
      float4v sres2[4];
      QK_PHASE(kt, 1, sres2);
      if (kt < 15) LOADK(kt + 1);
      EXP_PACK(1, sres2);
      PV_PHASE(0);
      PV_PHASE(1);
      if (kt < 15) LOADV(kt + 1);
    }

#pragma unroll
    for (int s = 0; s < 2; s++) {
#pragma unroll
      for (int r2 = 0; r2 < 4; r2++) {
        float linv = 1.0f / accl[s][r2];
        size_t rowaddr =
            ((size_t)b * 1024 + row0 + s * 16 + quad * 4 + r2) * 256 +
            h * 32;
        a.ao[rowaddr + l] = (half_t)(o0[s][r2] * linv);
        a.ao[rowaddr + 16 + l] = (half_t)(o1[s][r2] * linv);
      }
    }
  }
  grid_barrier(a.bar, a.bar + 1, 1024u);

  // ======== phase 3: proj (id -> bx 0..511, hf 0..1) =======================
  {
    float* yt = (float*)smem_raw;  // [128][36] f32, 18432 B
    int bx = id & 511, hf = id >> 9;
    int lane = t & 63, wv = t >> 6, l = lane & 15, quad = lane >> 4;
    int rw = wv & 1, cw = wv >> 1;
    int m0 = bx * 32;
    int b = m0 >> 10, n0 = m0 & 1023;

    half8 afr[4];
    const half_t* ab =
        a.ao + ((size_t)m0 + rw * 16 + l) * 256 + hf * 128 + quad * 8;
#pragma unroll
    for (int ks = 0; ks < 4; ks++) afr[ks] = *(const half8*)(ab + ks * 32);

    const half_t* wfb = a.wf + (6 + hf) * 16384;
#pragma unroll
    for (int ngl = 0; ngl < 4; ngl++) {
      int ng = cw * 4 + ngl;
      float4v c = {0.f, 0.f, 0.f, 0.f};
#pragma unroll
      for (int ks = 0; ks < 4; ks++) {
        half8 bfrag = *(const half8*)(wfb + ((ng * 4 + ks) * 64 + lane) * 8);
        c = mfma16(afr[ks], bfrag, c);
      }
      float bb = a.bws[(6 + hf) * 128 + ng * 16 + l];
#pragma unroll
      for (int r2 = 0; r2 < 4; r2++) c[r2] += bb;
      *(float4v*)(yt + (ng * 16 + l) * 36 + rw * 16 + quad * 4) = c;
    }
    __syncthreads();
#pragma unroll
    for (int i = 0; i < 4; i++) {
      int idx = t + 256 * i;
      int col = idx >> 3, rg = idx & 7;
      float4v vv = *(const float4v*)(yt + col * 36 + rg * 4);
      *(float4v*)(a.out + ((size_t)b * 256 + hf * 128 + col) * 1024 + n0 +
                  rg * 4) = vv;
    }
  }
}

// ---------------------------------------------------------------------------
extern "C" void kernel_launch(void* const* d_in, const int* in_sizes, int n_in,
                              void* d_out, int out_size, void* d_ws,
                              size_t ws_size, hipStream_t stream) {
  (void)in_sizes; (void)n_in; (void)out_size; (void)ws_size;

  half_t* ws = (half_t*)d_ws;
  FusedArgs fa;
  fa.x = (const float*)d_in[0];
  const int widx[8] = {1, 3, 5, 7, 9, 11, 13, 15};
  for (int i = 0; i < 8; i++) {
    fa.wsrc[i] = (const float*)d_in[widx[i]];
    fa.bsrc[i] = (const float*)d_in[widx[i] + 1];
  }
  fa.ls = (const float*)d_in[17];
  fa.w1 = (const float*)d_in[18];
  fa.b1 = (const float*)d_in[19];
  fa.w2 = (const float*)d_in[20];
  fa.qf = ws;                    // [16][8][1024][32] f16
  fa.kf = ws + 4194304;          // [16][8][1024][32] f16
  fa.vf = ws + 8388608;          // [16][8][32][1024] f16 (permuted)
  fa.ao = ws + 12582912;         // [16384][256] f16
  fa.wf = ws + 16777216;         // 8 x 16384 f16, fragment layout
  fa.tabd = (float*)((char*)d_ws + 33816576);  // [8][3970][2] f32
  fa.bws = (float*)((char*)d_ws + 34070656);   // [8][128] f32
  fa.bar = (unsigned*)((char*)d_ws + 34078720);  // {cnt, gen}
  fa.out = (float*)d_out;

  hipMemsetAsync((void*)fa.bar, 0, 64, stream);
  fused_all<<<dim3(1024), dim3(256), 0, stream>>>(fa);
}

// Round 13
// 193.751 us; speedup vs baseline: 3.6275x; 3.6275x over previous
//
#include <hip/hip_runtime.h>
#include <cmath>

// ---------------------------------------------------------------------------
// SwinV2-style window attention, f16-MFMA implementation.  Round 19.
//
// R18 (software-barrier fused) = 702us: grid barriers cost ~450us (polling
// + cross-XCD invalidates).  Fusion refuted both ways; back to 4 dispatches.
// R19 = R16 + qkv OP-MERGE: all 3 linears' MFMAs in ONE 48-MFMA stretch
// (acc[3][4]), q&k normed together, BOTH transposes in a doubled 17.4KB
// tbuf, stored after ONE barrier.  Barriers/block 6 -> 3, 3x MFMA issue
// density.  attn/proj/prep verbatim R16.
// ---------------------------------------------------------------------------

typedef _Float16 half_t;
typedef __attribute__((ext_vector_type(2))) __fp16 fp16x2;
typedef __attribute__((ext_vector_type(4))) _Float16 half4;
typedef __attribute__((ext_vector_type(8))) _Float16 half8;
typedef __attribute__((ext_vector_type(2))) float float2v;
typedef __attribute__((ext_vector_type(4))) float float4v;
typedef __attribute__((ext_vector_type(4))) unsigned int uint4v;

static __device__ __forceinline__ float4v mfma16(half8 a, half8 b, float4v c) {
  return __builtin_amdgcn_mfma_f32_16x16x32_f16(a, b, c, 0, 0, 0);
}

struct PtrArr8 { const float* p[8]; };

// ---------------------------------------------------------------------------
// prep_all: blocks 0..127 = prep_w (fp32 W -> f16 (+I), pre-fragmented
// B-layout + bias pack); blocks 128..143 = bias_mlp -> tabd[h][p] =
// {tab[p-1], tab[p]} (pair-replicated, f32, 3970 entries/h).
// ---------------------------------------------------------------------------
__global__ __launch_bounds__(256) void prep_all(
    PtrArr8 wsrc, PtrArr8 bsrc, half_t* __restrict__ wf,
    float* __restrict__ bws, const float* __restrict__ w1,
    const float* __restrict__ b1, const float* __restrict__ w2,
    const float* __restrict__ ls, float* __restrict__ tabd) {
  __shared__ float smem[1408];  // bias branch: sw1[256] sb1[128] sw2[1024]
  int blk = blockIdx.x;
  int t = threadIdx.x;
  if (blk < 128) {
    int y = blk >> 4, xx = blk & 15;
    const float* src = nullptr;
    const float* bs = nullptr;
#pragma unroll
    for (int i = 0; i < 8; i++)
      if (i == y) { src = wsrc.p[i]; bs = bsrc.p[i]; }
    int flat = (xx * 256 + t) * 4;
    float4 w = *(const float4*)(src + flat);
    int j = flat >> 7, k = flat & 127;
    if (y < 6) {
      if (k == j)     w.x += 1.0f;
      if (k + 1 == j) w.y += 1.0f;
      if (k + 2 == j) w.z += 1.0f;
      if (k + 3 == j) w.w += 1.0f;
    }
    half4 h;
    h[0] = (half_t)w.x;
    h[1] = (half_t)w.y;
    h[2] = (half_t)w.z;
    h[3] = (half_t)w.w;
    int ng = j >> 4, l = j & 15, ks = k >> 5, quad = (k >> 3) & 3, o8 = k & 7;
    *(half4*)(wf + y * 16384 + ((ng * 4 + ks) * 64 + quad * 16 + l) * 8 +
              o8) = h;
    if (xx == 0 && t < 128) bws[y * 128 + t] = bs[t];
  } else {
    float* sw1 = smem;
    float* sb1 = smem + 256;
    float* sw2 = smem + 384;
    sw1[t] = w1[t];
    if (t < 128) sb1[t] = b1[t];
    for (int i = t; i < 1024; i += 256) sw2[i] = w2[i];
    __syncthreads();
    int p = (blk - 128) * 256 + t;
    if (p >= 3969) return;
    int ph = p / 63, pw = p % 63;
    float t0 = (float)(ph - 31) * (3.2f / 31.0f);
    float t1 = (float)(pw - 31) * (3.2f / 31.0f);
    t0 = copysignf(1.0f - __expf(-fabsf(t0)), t0);
    t1 = copysignf(1.0f - __expf(-fabsf(t1)), t1);
    float acc[8];
#pragma unroll
    for (int hh = 0; hh < 8; hh++) acc[hh] = 0.0f;
    for (int j = 0; j < 128; j++) {
      float hj = fmaxf(0.0f, t0 * sw1[2 * j] + t1 * sw1[2 * j + 1] + sb1[j]);
#pragma unroll
      for (int hh = 0; hh < 8; hh++) acc[hh] += hj * sw2[hh * 128 + j];
    }
    const float L2E = 1.44269504f;
#pragma unroll
    for (int hh = 0; hh < 8; hh++) {
      float scale = __expf(fminf(ls[hh], 4.6051702f));
      float c14 = 14.0f - (scale + 16.0f) * L2E;
      float bias = 16.0f / (1.0f + __expf(-acc[hh]));
      float v = bias * L2E + c14;
      float* td = tabd + hh * 7940;  // float2[3970] per h
      td[p * 2 + 1] = v;        // tabd[h][p].y   = tab[p]
      td[p * 2 + 2] = v;        // tabd[h][p+1].x = tab[p]
      if (p == 0) td[0] = 0.0f; // tabd[h][0].x   = 0 (tab[-1])
    }
  }
}

// ---------------------------------------------------------------------------
// qkv_mfma: 3 fused linears (residual folded into W), per-head q/k norm,
// q scaled by scale*log2e.  grid (512 rowtiles-of-32, 2 hf) x 256.
// R19: ALL THREE ops' MFMAs in one stretch (acc[3][4]); q+k transposes in
// a doubled tbuf -> barriers/block 6 -> 3.  x staged through LDS (R15).
// V written PRE-PERMUTED for attn's register-P PV step.
// ---------------------------------------------------------------------------
__global__ __launch_bounds__(256, 4) void qkv_mfma(
    const float* __restrict__ x, const half_t* __restrict__ wfrag,
    const float* __restrict__ lscale, const float* __restrict__ bws,
    half_t* __restrict__ qf, half_t* __restrict__ kf,
    half_t* __restrict__ vf) {
  __shared__ half_t tbuf[8704];  // x-stage [128][36] | q[32][136]+k[32][136]
                                 // | v [128][36]
  int t = threadIdx.x;
  int lane = t & 63, wv = t >> 6, l = lane & 15, quad = lane >> 4;
  int rw = wv & 1, cw = wv >> 1;
  int hf = blockIdx.y;
  int m0 = blockIdx.x * 32;
  int b = m0 >> 10, n0 = m0 & 1023;

  // stage x[rows n0..n0+31][this half's 128 ch] -> tbuf[ch][36] (coalesced)
  {
    const float* xb = x + ((size_t)b * 256 + hf * 128) * 1024 + n0;
    int ch = t >> 3, no = (t & 7) * 4;
#pragma unroll
    for (int p = 0; p < 4; p++) {
      float4 v = *(const float4*)(xb + (size_t)(p * 32 + ch) * 1024 + no);
      half4 h;
      h[0] = (half_t)v.x;
      h[1] = (half_t)v.y;
      h[2] = (half_t)v.z;
      h[3] = (half_t)v.w;
      *(half4*)(tbuf + (p * 32 + ch) * 36 + no) = h;
    }
  }
  __syncthreads();

  // A fragments: 16 rows (rw strip), this half's 128 channels, from LDS.
  half8 afr[4];
#pragma unroll
  for (int ks = 0; ks < 4; ks++) {
    half8 a;
#pragma unroll
    for (int j = 0; j < 8; j++)
      a[j] = tbuf[(ks * 32 + quad * 8 + j) * 36 + rw * 16 + l];
    afr[ks] = a;
  }
  __syncthreads();  // xs dead; tbuf reused below

  // ---- one 48-MFMA stretch over all 3 ops ----
  float4v acc[3][4];
#pragma unroll
  for (int op = 0; op < 3; op++) {
    const half_t* wfb = wfrag + (op * 2 + hf) * 16384;
#pragma unroll
    for (int ngl = 0; ngl < 4; ngl++) {
      int ng = cw * 4 + ngl;
      float4v c = {0.f, 0.f, 0.f, 0.f};
#pragma unroll
      for (int ks = 0; ks < 4; ks++) {
        half8 bfrag =
            *(const half8*)(wfb + ((ng * 4 + ks) * 64 + lane) * 8);
        c = mfma16(afr[ks], bfrag, c);
      }
      acc[op][ngl] = c;
    }
  }
#pragma unroll
  for (int op = 0; op < 3; op++)
#pragma unroll
    for (int ngl = 0; ngl < 4; ngl++) {
      float bb = bws[(op * 2 + hf) * 128 + (cw * 4 + ngl) * 16 + l];
#pragma unroll
      for (int r2 = 0; r2 < 4; r2++) acc[op][ngl][r2] += bb;
    }

  // ---- q & k norms (heads hf*4 + cw*2 + {0,1}) ----
#pragma unroll
  for (int op = 0; op < 2; op++)
#pragma unroll
    for (int hgl = 0; hgl < 2; hgl++) {
      float sc = 1.0f;
      if (op == 0)
        sc = __expf(fminf(lscale[hf * 4 + cw * 2 + hgl], 4.6051702f)) *
             1.44269504f;
#pragma unroll
      for (int r2 = 0; r2 < 4; r2++) {
        float ss = acc[op][2 * hgl][r2] * acc[op][2 * hgl][r2] +
                   acc[op][2 * hgl + 1][r2] * acc[op][2 * hgl + 1][r2];
        ss += __shfl_xor(ss, 1, 64);
        ss += __shfl_xor(ss, 2, 64);
        ss += __shfl_xor(ss, 4, 64);
        ss += __shfl_xor(ss, 8, 64);
        float rn = sc / fmaxf(sqrtf(ss), 1e-12f);
        acc[op][2 * hgl][r2] *= rn;
        acc[op][2 * hgl + 1][r2] *= rn;
      }
    }

  // ---- q+k transposes together: tbuf[op*4352 + row*136 + col] ----
#pragma unroll
  for (int op = 0; op < 2; op++)
#pragma unroll
    for (int ngl = 0; ngl < 4; ngl++)
#pragma unroll
      for (int r2 = 0; r2 < 4; r2++)
        tbuf[op * 4352 + (rw * 16 + quad * 4 + r2) * 136 +
             (cw * 4 + ngl) * 16 + l] = (half_t)acc[op][ngl][r2];
  __syncthreads();
#pragma unroll
  for (int op = 0; op < 2; op++) {
    half_t* dst = (op == 0) ? qf : kf;
#pragma unroll
    for (int i = 0; i < 2; i++) {
      int idx = t + 256 * i;
      int row = idx >> 4, colc = (idx & 15) * 8;
      half8 vv = *(const half8*)(tbuf + op * 4352 + row * 136 + colc);
      int head = hf * 4 + (colc >> 5), d = colc & 31;
      *(half8*)(dst + (((size_t)b * 8 + head) * 1024 + n0 + row) * 32 + d) =
          vv;
    }
  }
  __syncthreads();

  // ---- v: [col128][row32] stride 36 -> permuted dword to [b][h][d][n~] ----
#pragma unroll
  for (int ngl = 0; ngl < 4; ngl++) {
    int col = (cw * 4 + ngl) * 16 + l;
    half4 hv;
#pragma unroll
    for (int r2 = 0; r2 < 4; r2++) hv[r2] = (half_t)acc[2][ngl][r2];
    *(half4*)(tbuf + col * 36 + rw * 16 + quad * 4) = hv;
  }
  __syncthreads();
  int p64 = (n0 >> 5) & 1;
  int nb64 = n0 & ~63;
#pragma unroll
  for (int i = 0; i < 8; i++) {
    int idx = t + 256 * i;
    int col = idx >> 4, rp = idx & 15;
    unsigned int val = *(const unsigned int*)(tbuf + col * 36 + rp * 2);
    int head = hf * 4 + (col >> 5);
    int d = col & 31;
    // key_local = rp*2+e, bits [a0 q1 q0 ks e] -> s = q*16+ks*8+a*2+e
    int npos = nb64 + ((rp >> 1) & 3) * 16 + (rp & 1) * 8 + p64 * 4 +
               ((rp >> 3) & 1) * 2;
    *(unsigned int*)((char*)vf +
                     (((((size_t)b * 8 + head) * 32 + d) * 1024) + npos) *
                         2) = val;
  }
}

// ---------------------------------------------------------------------------
// attn_mfma: barrier-free flash attention, XCD-local K/V, register-resident
// P.  1-D grid 1024: id = qo*128 + (b*8+h) -> the 8 qo-blocks of one (b,h)
// are congruent mod 8 -> same XCD -> K/V L2-resident.  256 thr (4 waves),
// wave owns 32 q-rows.  P~ = exp2(QK + biastab) via raw v_exp_f32, packs
// straight into the PV A-operand (V pre-permuted).  Softmax denom via
// ones-column MFMA.  Bias: sb2d float2 pair table, staged as a coalesced
// b64 copy from the prebuilt global tabd.  K/V single-buffered registers.
// ---------------------------------------------------------------------------

#define LOADK(kt)                                                           \
  {                                                                         \
    _Pragma("unroll") for (int nt = 0; nt < 4; nt++)                        \
        kfr[nt] = *(const half8*)(kbase + ((kt)*64 + nt * 16 + l) * 32 +    \
                                  quad * 8);                                \
  }

#define LOADV(kt)                                                           \
  {                                                                         \
    _Pragma("unroll") for (int ks = 0; ks < 2; ks++) {                      \
      vv0[ks] = *(const half8*)(vbase + l * 1024 + (kt)*64 + quad * 16 +    \
                                ks * 8);                                    \
      vv1[ks] = *(const half8*)(vbase + (16 + l) * 1024 + (kt)*64 +         \
                                quad * 16 + ks * 8);                        \
    }                                                                       \
  }

#define QK_PHASE(kt, S, SR)                                                 \
  {                                                                         \
    int rowb = (wv + 31 - 2 * (kt)) * 63 + cA + (S)*16;                     \
    _Pragma("unroll") for (int nt = 0; nt < 4; nt++) {                      \
      int base = rowb - (nt >> 1) * 63 - (nt & 1) * 16;                     \
      float2v p0 = sb2d[base];                                              \
      float2v p1 = sb2d[base - 2];                                          \
      float4v c;                                                            \
      c[0] = p0[1];                                                         \
      c[1] = p0[0];                                                         \
      c[2] = p1[1];                                                         \
      c[3] = p1[0];                                                         \
      SR[nt] = mfma16(kfr[nt], qfr[S], c);                                  \
    }                                                                       \
  }

#define EXP_PACK(S, SR)                                                     \
  {                                                                         \
    unsigned int w0[4], w1[4];                                              \
    _Pragma("unroll") for (int nt = 0; nt < 4; nt++) {                      \
      fp16x2 plo = __builtin_amdgcn_cvt_pkrtz(                              \
          __builtin_amdgcn_exp2f(SR[nt][0]),                                \
          __builtin_amdgcn_exp2f(SR[nt][1]));                               \
      fp16x2 phi = __builtin_amdgcn_cvt_pkrtz(                              \
          __builtin_amdgcn_exp2f(SR[nt][2]),                                \
          __builtin_amdgcn_exp2f(SR[nt][3]));                               \
      w0[nt] = __builtin_bit_cast(unsigned int, plo);                       \
      w1[nt] = __builtin_bit_cast(unsigned int, phi);                       \
    }                                                                       \
    uint4v u0 = {w0[0], w0[1], w0[2], w0[3]};                               \
    uint4v u1 = {w1[0], w1[1], w1[2], w1[3]};                               \
    pf##S[0] = __builtin_bit_cast(half8, u0);                               \
    pf##S[1] = __builtin_bit_cast(half8, u1);                               \
  }

#define PV_PHASE(S)                                                         \
  {                                                                         \
    _Pragma("unroll") for (int ks = 0; ks < 2; ks++) {                      \
      o0[S] = mfma16(pf##S[ks], vv0[ks], o0[S]);                            \
      o1[S] = mfma16(pf##S[ks], vv1[ks], o1[S]);                            \
      accl[S] = mfma16(pf##S[ks], ones, accl[S]);                           \
    }                                                                       \
  }

__global__ __launch_bounds__(256) void attn_mfma(
    const half_t* __restrict__ qf, const half_t* __restrict__ kf,
    const half_t* __restrict__ vf, const float* __restrict__ tabd,
    half_t* __restrict__ ao) {
  __shared__ float2v sb2d[2205];  // bias pairs {tab[i-1], tab[i]}, 17.6KB

  int id = blockIdx.x;
  int qo = id >> 7;
  int bh = id & 127;
  int h = bh & 7, b = bh >> 3;
  int t = threadIdx.x;
  int lane = t & 63, wv = t >> 6, l = lane & 15, quad = lane >> 4;
  size_t bhs = (size_t)b * 8 + h;
  const half_t* kbase = kf + bhs * 1024 * 32;
  const half_t* vbase = vf + bhs * 32 * 1024;
  int row0 = qo * 128 + wv * 32;
  int cA = l + 31 - quad * 4;

  half8 kfr[4], vv0[2], vv1[2], qfr[2], pf0[2], pf1[2];
  LOADK(0);
  LOADV(0);
#pragma unroll
  for (int s = 0; s < 2; s++)
    qfr[s] = *(const half8*)(qf + (bhs * 1024 + row0 + s * 16 + l) * 32 +
                             quad * 8);

  // stage bias pairs: straight coalesced b64 copy from prebuilt tabd
  {
    const float2v* td =
        (const float2v*)(tabd + (size_t)h * 7940) + qo * 252;
    for (int i = t; i < 2205; i += 256) sb2d[i] = td[i];
  }

  float4v o0[2], o1[2], accl[2];
#pragma unroll
  for (int s = 0; s < 2; s++) {
    o0[s] = (float4v){0.f, 0.f, 0.f, 0.f};
    o1[s] = (float4v){0.f, 0.f, 0.f, 0.f};
    accl[s] = (float4v){0.f, 0.f, 0.f, 0.f};
  }
  half8 ones;
#pragma unroll
  for (int j = 0; j < 8; j++) ones[j] = (half_t)1.0f;

  __syncthreads();  // the ONLY barrier

#pragma unroll
  for (int kt = 0; kt < 16; ++kt) {
    float4v sres[4];
    QK_PHASE(kt, 0, sres);
    EXP_PACK(0, sres);
    float4v sres2[4];
    QK_PHASE(kt, 1, sres2);
    if (kt < 15) LOADK(kt + 1);  // kfr consumed by QK above
    EXP_PACK(1, sres2);
    PV_PHASE(0);
    PV_PHASE(1);
    if (kt < 15) LOADV(kt + 1);  // vv consumed by PV above
  }

#pragma unroll
  for (int s = 0; s < 2; s++) {
#pragma unroll
    for (int r2 = 0; r2 < 4; r2++) {
      float linv = 1.0f / accl[s][r2];
      size_t rowaddr =
          ((size_t)b * 1024 + row0 + s * 16 + quad * 4 + r2) * 256 + h * 32;
      ao[rowaddr + l] = (half_t)(o0[s][r2] * linv);
      ao[rowaddr + 16 + l] = (half_t)(o1[s][r2] * linv);
    }
  }
}

// ---------------------------------------------------------------------------
// proj_mfma: output projection, fp32 out [b][ch][n] via LDS transpose.
// grid (512 rowtiles-of-32, 2 hf) x 256.  W-frags direct from global.
// ---------------------------------------------------------------------------
__global__ __launch_bounds__(256, 4) void proj_mfma(
    const half_t* __restrict__ ao, const half_t* __restrict__ wfrag,
    const float* __restrict__ bws, float* __restrict__ out) {
  __shared__ float yt[128 * 36];
  int t = threadIdx.x;
  int lane = t & 63, wv = t >> 6, l = lane & 15, quad = lane >> 4;
  int rw = wv & 1, cw = wv >> 1;
  int hf = blockIdx.y;
  int m0 = blockIdx.x * 32;
  int b = m0 >> 10, n0 = m0 & 1023;

  half8 afr[4];
  const half_t* ab =
      ao + ((size_t)m0 + rw * 16 + l) * 256 + hf * 128 + quad * 8;
#pragma unroll
  for (int ks = 0; ks < 4; ks++) afr[ks] = *(const half8*)(ab + ks * 32);

  const half_t* wfb = wfrag + (6 + hf) * 16384;
#pragma unroll
  for (int ngl = 0; ngl < 4; ngl++) {
    int ng = cw * 4 + ngl;
    float4v c = {0.f, 0.f, 0.f, 0.f};
#pragma unroll
    for (int ks = 0; ks < 4; ks++) {
      half8 bfrag = *(const half8*)(wfb + ((ng * 4 + ks) * 64 + lane) * 8);
      c = mfma16(afr[ks], bfrag, c);
    }
    float bb = bws[(6 + hf) * 128 + ng * 16 + l];
#pragma unroll
    for (int r2 = 0; r2 < 4; r2++) c[r2] += bb;
    *(float4v*)(yt + (ng * 16 + l) * 36 + rw * 16 + quad * 4) = c;
  }
  __syncthreads();
#pragma unroll
  for (int i = 0; i < 4; i++) {
    int idx = t + 256 * i;
    int col = idx >> 3, rg = idx & 7;
    float4v vv = *(const float4v*)(yt + col * 36 + rg * 4);
    *(float4v*)(out + ((size_t)b * 256 + hf * 128 + col) * 1024 + n0 +
                rg * 4) = vv;
  }
}

// ---------------------------------------------------------------------------
extern "C" void kernel_launch(void* const* d_in, const int* in_sizes, int n_in,
                              void* d_out, int out_size, void* d_ws,
                              size_t ws_size, hipStream_t stream) {
  (void)in_sizes; (void)n_in; (void)out_size; (void)ws_size;
  const float* x = (const float*)d_in[0];

  half_t* ws = (half_t*)d_ws;
  half_t* qfp = ws;                    // [16][8][1024][32] f16
  half_t* kfp = ws + 4194304;          // [16][8][1024][32] f16
  half_t* vfp = ws + 8388608;          // [16][8][32][1024] f16 (permuted)
  half_t* aop = ws + 12582912;         // [16384][256] f16
  half_t* wfp = ws + 16777216;         // 8 x 16384 f16, fragment layout
  float* tabd = (float*)((char*)d_ws + 33816576);   // [8][3970][2] f32
  float* bws = (float*)((char*)d_ws + 34070656);    // [8][128] f32

  PtrArr8 wsrc, bsrc;
  const int widx[8] = {1, 3, 5, 7, 9, 11, 13, 15};
  for (int i = 0; i < 8; i++) {
    wsrc.p[i] = (const float*)d_in[widx[i]];
    bsrc.p[i] = (const float*)d_in[widx[i] + 1];
  }

  prep_all<<<144, 256, 0, stream>>>(wsrc, bsrc, wfp, bws,
                                    (const float*)d_in[18],
                                    (const float*)d_in[19],
                                    (const float*)d_in[20],
                                    (const float*)d_in[17], tabd);
  qkv_mfma<<<dim3(512, 2), 256, 0, stream>>>(x, wfp, (const float*)d_in[17],
                                             bws, qfp, kfp, vfp);
  attn_mfma<<<1024, 256, 0, stream>>>(qfp, kfp, vfp, tabd, aop);
  proj_mfma<<<dim3(512, 2), 256, 0, stream>>>(aop, wfp, bws, (float*)d_out);
}

// Round 14
// 188.404 us; speedup vs baseline: 3.7305x; 1.0284x over previous
//
#include <hip/hip_runtime.h>
#include <cmath>

// ---------------------------------------------------------------------------
// SwinV2-style window attention, f16-MFMA implementation.  Round 20.
//
// R19 (qkv op-merge) regressed ~4us (likely VGPR spill past the 128 cap);
// qkv reverted to R16.  R20 = R16 + SPLIT-K ATTENTION: this softmax has no
// running max (fixed c14 recentering), so partial (o, accl) over disjoint
// key ranges merge by PURE ADDITION.  Block = 512 thr / 8 waves = 4
// q-strips x 2 k-halves; each wave does 8 kt (was 16) -> serial k-chain
// halved, L2 traffic UNCHANGED (unlike R13), waves/CU 16 -> ~24.
// Merge: wk=1 waves write o0/o1/accl to a separate 24.6KB LDS region,
// one barrier, wk=0 adds + normalizes + stores.  prep/qkv/proj = R16.
// ---------------------------------------------------------------------------

typedef _Float16 half_t;
typedef __attribute__((ext_vector_type(2))) __fp16 fp16x2;
typedef __attribute__((ext_vector_type(4))) _Float16 half4;
typedef __attribute__((ext_vector_type(8))) _Float16 half8;
typedef __attribute__((ext_vector_type(2))) float float2v;
typedef __attribute__((ext_vector_type(4))) float float4v;
typedef __attribute__((ext_vector_type(4))) unsigned int uint4v;

static __device__ __forceinline__ float4v mfma16(half8 a, half8 b, float4v c) {
  return __builtin_amdgcn_mfma_f32_16x16x32_f16(a, b, c, 0, 0, 0);
}

struct PtrArr8 { const float* p[8]; };

// ---------------------------------------------------------------------------
// prep_all: blocks 0..127 = prep_w (fp32 W -> f16 (+I), pre-fragmented
// B-layout + bias pack); blocks 128..143 = bias_mlp -> tabd[h][p] =
// {tab[p-1], tab[p]} (pair-replicated, f32, 3970 entries/h).
// ---------------------------------------------------------------------------
__global__ __launch_bounds__(256) void prep_all(
    PtrArr8 wsrc, PtrArr8 bsrc, half_t* __restrict__ wf,
    float* __restrict__ bws, const float* __restrict__ w1,
    const float* __restrict__ b1, const float* __restrict__ w2,
    const float* __restrict__ ls, float* __restrict__ tabd) {
  __shared__ float smem[1408];  // bias branch: sw1[256] sb1[128] sw2[1024]
  int blk = blockIdx.x;
  int t = threadIdx.x;
  if (blk < 128) {
    int y = blk >> 4, xx = blk & 15;
    const float* src = nullptr;
    const float* bs = nullptr;
#pragma unroll
    for (int i = 0; i < 8; i++)
      if (i == y) { src = wsrc.p[i]; bs = bsrc.p[i]; }
    int flat = (xx * 256 + t) * 4;
    float4 w = *(const float4*)(src + flat);
    int j = flat >> 7, k = flat & 127;
    if (y < 6) {
      if (k == j)     w.x += 1.0f;
      if (k + 1 == j) w.y += 1.0f;
      if (k + 2 == j) w.z += 1.0f;
      if (k + 3 == j) w.w += 1.0f;
    }
    half4 h;
    h[0] = (half_t)w.x;
    h[1] = (half_t)w.y;
    h[2] = (half_t)w.z;
    h[3] = (half_t)w.w;
    int ng = j >> 4, l = j & 15, ks = k >> 5, quad = (k >> 3) & 3, o8 = k & 7;
    *(half4*)(wf + y * 16384 + ((ng * 4 + ks) * 64 + quad * 16 + l) * 8 +
              o8) = h;
    if (xx == 0 && t < 128) bws[y * 128 + t] = bs[t];
  } else {
    float* sw1 = smem;
    float* sb1 = smem + 256;
    float* sw2 = smem + 384;
    sw1[t] = w1[t];
    if (t < 128) sb1[t] = b1[t];
    for (int i = t; i < 1024; i += 256) sw2[i] = w2[i];
    __syncthreads();
    int p = (blk - 128) * 256 + t;
    if (p >= 3969) return;
    int ph = p / 63, pw = p % 63;
    float t0 = (float)(ph - 31) * (3.2f / 31.0f);
    float t1 = (float)(pw - 31) * (3.2f / 31.0f);
    t0 = copysignf(1.0f - __expf(-fabsf(t0)), t0);
    t1 = copysignf(1.0f - __expf(-fabsf(t1)), t1);
    float acc[8];
#pragma unroll
    for (int hh = 0; hh < 8; hh++) acc[hh] = 0.0f;
    for (int j = 0; j < 128; j++) {
      float hj = fmaxf(0.0f, t0 * sw1[2 * j] + t1 * sw1[2 * j + 1] + sb1[j]);
#pragma unroll
      for (int hh = 0; hh < 8; hh++) acc[hh] += hj * sw2[hh * 128 + j];
    }
    const float L2E = 1.44269504f;
#pragma unroll
    for (int hh = 0; hh < 8; hh++) {
      float scale = __expf(fminf(ls[hh], 4.6051702f));
      float c14 = 14.0f - (scale + 16.0f) * L2E;
      float bias = 16.0f / (1.0f + __expf(-acc[hh]));
      float v = bias * L2E + c14;
      float* td = tabd + hh * 7940;  // float2[3970] per h
      td[p * 2 + 1] = v;        // tabd[h][p].y   = tab[p]
      td[p * 2 + 2] = v;        // tabd[h][p+1].x = tab[p]
      if (p == 0) td[0] = 0.0f; // tabd[h][0].x   = 0 (tab[-1])
    }
  }
}

// ---------------------------------------------------------------------------
// qkv_mfma: 3 fused linears (residual folded into W), per-head q/k norm,
// q scaled by scale*log2e.  grid (512 rowtiles-of-32, 2 hf) x 256.
// x staged through LDS (coalesced float4) -> A-frags via LDS scalar reads.
// V written PRE-PERMUTED for attn's register-P PV step.
// ---------------------------------------------------------------------------
__global__ __launch_bounds__(256, 4) void qkv_mfma(
    const float* __restrict__ x, const half_t* __restrict__ wfrag,
    const float* __restrict__ lscale, const float* __restrict__ bws,
    half_t* __restrict__ qf, half_t* __restrict__ kf,
    half_t* __restrict__ vf) {
  __shared__ half_t tbuf[4608];  // x-stage [128][36]; then q/k [32][136],
                                 // v [128][36]
  int t = threadIdx.x;
  int lane = t & 63, wv = t >> 6, l = lane & 15, quad = lane >> 4;
  int rw = wv & 1, cw = wv >> 1;
  int hf = blockIdx.y;
  int m0 = blockIdx.x * 32;
  int b = m0 >> 10, n0 = m0 & 1023;

  // stage x[rows n0..n0+31][this half's 128 ch] -> tbuf[ch][36] (coalesced)
  {
    const float* xb = x + ((size_t)b * 256 + hf * 128) * 1024 + n0;
    int ch = t >> 3, no = (t & 7) * 4;
#pragma unroll
    for (int p = 0; p < 4; p++) {
      float4 v = *(const float4*)(xb + (size_t)(p * 32 + ch) * 1024 + no);
      half4 h;
      h[0] = (half_t)v.x;
      h[1] = (half_t)v.y;
      h[2] = (half_t)v.z;
      h[3] = (half_t)v.w;
      *(half4*)(tbuf + (p * 32 + ch) * 36 + no) = h;
    }
  }
  __syncthreads();

  // A fragments: 16 rows (rw strip), this half's 128 channels, from LDS.
  half8 afr[4];
#pragma unroll
  for (int ks = 0; ks < 4; ks++) {
    half8 a;
#pragma unroll
    for (int j = 0; j < 8; j++)
      a[j] = tbuf[(ks * 32 + quad * 8 + j) * 36 + rw * 16 + l];
    afr[ks] = a;
  }
  __syncthreads();  // xs dead; tbuf reused by epilogues below

  for (int op = 0; op < 3; op++) {
    int combo = op * 2 + hf;
    const half_t* wfb = wfrag + combo * 16384;
    float4v acc[4];
#pragma unroll
    for (int ngl = 0; ngl < 4; ngl++) {
      int ng = cw * 4 + ngl;
      float4v c = {0.f, 0.f, 0.f, 0.f};
#pragma unroll
      for (int ks = 0; ks < 4; ks++) {
        half8 bfrag =
            *(const half8*)(wfb + ((ng * 4 + ks) * 64 + lane) * 8);
        c = mfma16(afr[ks], bfrag, c);
      }
      acc[ngl] = c;
    }
#pragma unroll
    for (int ngl = 0; ngl < 4; ngl++) {
      float bb = bws[combo * 128 + (cw * 4 + ngl) * 16 + l];
#pragma unroll
      for (int r2 = 0; r2 < 4; r2++) acc[ngl][r2] += bb;
    }
    if (op < 2) {
      // normalize per head: this wave's heads = hf*4 + cw*2 + {0,1}
#pragma unroll
      for (int hgl = 0; hgl < 2; hgl++) {
        float sc = 1.0f;
        if (op == 0)
          sc = __expf(fminf(lscale[hf * 4 + cw * 2 + hgl], 4.6051702f)) *
               1.44269504f;
#pragma unroll
        for (int r2 = 0; r2 < 4; r2++) {
          float ss = acc[2 * hgl][r2] * acc[2 * hgl][r2] +
                     acc[2 * hgl + 1][r2] * acc[2 * hgl + 1][r2];
          ss += __shfl_xor(ss, 1, 64);
          ss += __shfl_xor(ss, 2, 64);
          ss += __shfl_xor(ss, 4, 64);
          ss += __shfl_xor(ss, 8, 64);
          float rn = sc / fmaxf(sqrtf(ss), 1e-12f);
          acc[2 * hgl][r2] *= rn;
          acc[2 * hgl + 1][r2] *= rn;
        }
      }
      // transpose via LDS [row32][col128] stride 136 -> coalesced half8
#pragma unroll
      for (int ngl = 0; ngl < 4; ngl++)
#pragma unroll
        for (int r2 = 0; r2 < 4; r2++)
          tbuf[(rw * 16 + quad * 4 + r2) * 136 + (cw * 4 + ngl) * 16 + l] =
              (half_t)acc[ngl][r2];
      __syncthreads();
      half_t* dst = (op == 0) ? qf : kf;
#pragma unroll
      for (int i = 0; i < 2; i++) {
        int idx = t + 256 * i;
        int row = idx >> 4, colc = (idx & 15) * 8;
        half8 vv = *(const half8*)(tbuf + row * 136 + colc);
        int head = hf * 4 + (colc >> 5), d = colc & 31;
        *(half8*)(dst + (((size_t)b * 8 + head) * 1024 + n0 + row) * 32 + d) =
            vv;
      }
      __syncthreads();
    } else {
      // v: [col128][row32] stride 36 -> permuted dword to [b][h][d][n~]
#pragma unroll
      for (int ngl = 0; ngl < 4; ngl++) {
        int col = (cw * 4 + ngl) * 16 + l;
        half4 hv;
#pragma unroll
        for (int r2 = 0; r2 < 4; r2++) hv[r2] = (half_t)acc[ngl][r2];
        *(half4*)(tbuf + col * 36 + rw * 16 + quad * 4) = hv;
      }
      __syncthreads();
      int p64 = (n0 >> 5) & 1;
      int nb64 = n0 & ~63;
#pragma unroll
      for (int i = 0; i < 8; i++) {
        int idx = t + 256 * i;
        int col = idx >> 4, rp = idx & 15;
        unsigned int val = *(const unsigned int*)(tbuf + col * 36 + rp * 2);
        int head = hf * 4 + (col >> 5);
        int d = col & 31;
        // key_local = rp*2+e, bits [a0 q1 q0 ks e] -> s = q*16+ks*8+a*2+e
        int npos = nb64 + ((rp >> 1) & 3) * 16 + (rp & 1) * 8 + p64 * 4 +
                   ((rp >> 3) & 1) * 2;
        *(unsigned int*)((char*)vf +
                         (((((size_t)b * 8 + head) * 32 + d) * 1024) + npos) *
                             2) = val;
      }
    }
  }
}

// ---------------------------------------------------------------------------
// attn_mfma: SPLIT-K flash attention, XCD-local K/V, register-resident P.
// grid 1024 x 512 thr (8 waves): wave (wq, wk) = q-strip wq*32 rows,
// keys kt in [wk*8, wk*8+8).  No running max (c14 recentering) -> partials
// merge by pure addition through LDS red[] after one barrier.
// ---------------------------------------------------------------------------

#define LOADK(kt)                                                           \
  {                                                                         \
    _Pragma("unroll") for (int nt = 0; nt < 4; nt++)                        \
        kfr[nt] = *(const half8*)(kbase + ((kt)*64 + nt * 16 + l) * 32 +    \
                                  quad * 8);                                \
  }

#define LOADV(kt)                                                           \
  {                                                                         \
    _Pragma("unroll") for (int ks = 0; ks < 2; ks++) {                      \
      vv0[ks] = *(const half8*)(vbase + l * 1024 + (kt)*64 + quad * 16 +    \
                                ks * 8);                                    \
      vv1[ks] = *(const half8*)(vbase + (16 + l) * 1024 + (kt)*64 +         \
                                quad * 16 + ks * 8);                        \
    }                                                                       \
  }

#define QK_PHASE(kt, S, SR)                                                 \
  {                                                                         \
    int rowb = (wq + 31 - 2 * (kt)) * 63 + cA + (S)*16;                     \
    _Pragma("unroll") for (int nt = 0; nt < 4; nt++) {                      \
      int base = rowb - (nt >> 1) * 63 - (nt & 1) * 16;                     \
      float2v p0 = sb2d[base];                                              \
      float2v p1 = sb2d[base - 2];                                          \
      float4v c;                                                            \
      c[0] = p0[1];                                                         \
      c[1] = p0[0];                                                         \
      c[2] = p1[1];                                                         \
      c[3] = p1[0];                                                         \
      SR[nt] = mfma16(kfr[nt], qfr[S], c);                                  \
    }                                                                       \
  }

#define EXP_PACK(S, SR)                                                     \
  {                                                                         \
    unsigned int w0[4], w1[4];                                              \
    _Pragma("unroll") for (int nt = 0; nt < 4; nt++) {                      \
      fp16x2 plo = __builtin_amdgcn_cvt_pkrtz(                              \
          __builtin_amdgcn_exp2f(SR[nt][0]),                                \
          __builtin_amdgcn_exp2f(SR[nt][1]));                               \
      fp16x2 phi = __builtin_amdgcn_cvt_pkrtz(                              \
          __builtin_amdgcn_exp2f(SR[nt][2]),                                \
          __builtin_amdgcn_exp2f(SR[nt][3]));                               \
      w0[nt] = __builtin_bit_cast(unsigned int, plo);                       \
      w1[nt] = __builtin_bit_cast(unsigned int, phi);                       \
    }                                                                       \
    uint4v u0 = {w0[0], w0[1], w0[2], w0[3]};                               \
    uint4v u1 = {w1[0], w1[1], w1[2], w1[3]};                               \
    pf##S[0] = __builtin_bit_cast(half8, u0);                               \
    pf##S[1] = __builtin_bit_cast(half8, u1);                               \
  }

#define PV_PHASE(S)                                                         \
  {                                                                         \
    _Pragma("unroll") for (int ks = 0; ks < 2; ks++) {                      \
      o0[S] = mfma16(pf##S[ks], vv0[ks], o0[S]);                            \
      o1[S] = mfma16(pf##S[ks], vv1[ks], o1[S]);                            \
      accl[S] = mfma16(pf##S[ks], ones, accl[S]);                           \
    }                                                                       \
  }

__global__ __launch_bounds__(512) void attn_mfma(
    const half_t* __restrict__ qf, const half_t* __restrict__ kf,
    const half_t* __restrict__ vf, const float* __restrict__ tabd,
    half_t* __restrict__ ao) {
  __shared__ float2v sb2d[2205];   // bias pairs {tab[i-1], tab[i]}, 17.6KB
  __shared__ float red[24 * 256];  // split-K partials, 24.6KB

  int id = blockIdx.x;
  int qo = id >> 7;
  int bh = id & 127;
  int h = bh & 7, b = bh >> 3;
  int t = threadIdx.x;
  int lane = t & 63, wv = t >> 6, l = lane & 15, quad = lane >> 4;
  int wq = wv & 3, wk = wv >> 2;  // q-strip, key-half
  size_t bhs = (size_t)b * 8 + h;
  const half_t* kbase = kf + bhs * 1024 * 32;
  const half_t* vbase = vf + bhs * 32 * 1024;
  int row0 = qo * 128 + wq * 32;
  int cA = l + 31 - quad * 4;
  int kt0 = wk * 8;

  half8 kfr[4], vv0[2], vv1[2], qfr[2], pf0[2], pf1[2];
  LOADK(kt0);
  LOADV(kt0);
#pragma unroll
  for (int s = 0; s < 2; s++)
    qfr[s] = *(const half8*)(qf + (bhs * 1024 + row0 + s * 16 + l) * 32 +
                             quad * 8);

  // stage bias pairs: straight coalesced b64 copy from prebuilt tabd
  {
    const float2v* td =
        (const float2v*)(tabd + (size_t)h * 7940) + qo * 252;
    for (int i = t; i < 2205; i += 512) sb2d[i] = td[i];
  }

  float4v o0[2], o1[2], accl[2];
#pragma unroll
  for (int s = 0; s < 2; s++) {
    o0[s] = (float4v){0.f, 0.f, 0.f, 0.f};
    o1[s] = (float4v){0.f, 0.f, 0.f, 0.f};
    accl[s] = (float4v){0.f, 0.f, 0.f, 0.f};
  }
  half8 ones;
#pragma unroll
  for (int j = 0; j < 8; j++) ones[j] = (half_t)1.0f;

  __syncthreads();  // bias staged

#pragma unroll
  for (int i = 0; i < 8; ++i) {
    int kt = kt0 + i;
    float4v sres[4];
    QK_PHASE(kt, 0, sres);
    EXP_PACK(0, sres);
    float4v sres2[4];
    QK_PHASE(kt, 1, sres2);
    if (i < 7) LOADK(kt + 1);  // kfr consumed by QK above
    EXP_PACK(1, sres2);
    PV_PHASE(0);
    PV_PHASE(1);
    if (i < 7) LOADV(kt + 1);  // vv consumed by PV above
  }

  // split-K merge: wk=1 publishes partials; wk=0 adds and stores.
  int rbase = wq * 64 + lane;
  if (wk == 1) {
#pragma unroll
    for (int s = 0; s < 2; s++)
#pragma unroll
      for (int r2 = 0; r2 < 4; r2++) {
        red[(s * 12 + r2) * 256 + rbase] = o0[s][r2];
        red[(s * 12 + 4 + r2) * 256 + rbase] = o1[s][r2];
        red[(s * 12 + 8 + r2) * 256 + rbase] = accl[s][r2];
      }
  }
  __syncthreads();
  if (wk == 0) {
#pragma unroll
    for (int s = 0; s < 2; s++) {
#pragma unroll
      for (int r2 = 0; r2 < 4; r2++) {
        o0[s][r2] += red[(s * 12 + r2) * 256 + rbase];
        o1[s][r2] += red[(s * 12 + 4 + r2) * 256 + rbase];
        accl[s][r2] += red[(s * 12 + 8 + r2) * 256 + rbase];
      }
    }
#pragma unroll
    for (int s = 0; s < 2; s++) {
#pragma unroll
      for (int r2 = 0; r2 < 4; r2++) {
        float linv = 1.0f / accl[s][r2];
        size_t rowaddr =
            ((size_t)b * 1024 + row0 + s * 16 + quad * 4 + r2) * 256 +
            h * 32;
        ao[rowaddr + l] = (half_t)(o0[s][r2] * linv);
        ao[rowaddr + 16 + l] = (half_t)(o1[s][r2] * linv);
      }
    }
  }
}

// ---------------------------------------------------------------------------
// proj_mfma: output projection, fp32 out [b][ch][n] via LDS transpose.
// grid (512 rowtiles-of-32, 2 hf) x 256.  W-frags direct from global.
// ---------------------------------------------------------------------------
__global__ __launch_bounds__(256, 4) void proj_mfma(
    const half_t* __restrict__ ao, const half_t* __restrict__ wfrag,
    const float* __restrict__ bws, float* __restrict__ out) {
  __shared__ float yt[128 * 36];
  int t = threadIdx.x;
  int lane = t & 63, wv = t >> 6, l = lane & 15, quad = lane >> 4;
  int rw = wv & 1, cw = wv >> 1;
  int hf = blockIdx.y;
  int m0 = blockIdx.x * 32;
  int b = m0 >> 10, n0 = m0 & 1023;

  half8 afr[4];
  const half_t* ab =
      ao + ((size_t)m0 + rw * 16 + l) * 256 + hf * 128 + quad * 8;
#pragma unroll
  for (int ks = 0; ks < 4; ks++) afr[ks] = *(const half8*)(ab + ks * 32);

  const half_t* wfb = wfrag + (6 + hf) * 16384;
#pragma unroll
  for (int ngl = 0; ngl < 4; ngl++) {
    int ng = cw * 4 + ngl;
    float4v c = {0.f, 0.f, 0.f, 0.f};
#pragma unroll
    for (int ks = 0; ks < 4; ks++) {
      half8 bfrag = *(const half8*)(wfb + ((ng * 4 + ks) * 64 + lane) * 8);
      c = mfma16(afr[ks], bfrag, c);
    }
    float bb = bws[(6 + hf) * 128 + ng * 16 + l];
#pragma unroll
    for (int r2 = 0; r2 < 4; r2++) c[r2] += bb;
    *(float4v*)(yt + (ng * 16 + l) * 36 + rw * 16 + quad * 4) = c;
  }
  __syncthreads();
#pragma unroll
  for (int i = 0; i < 4; i++) {
    int idx = t + 256 * i;
    int col = idx >> 3, rg = idx & 7;
    float4v vv = *(const float4v*)(yt + col * 36 + rg * 4);
    *(float4v*)(out + ((size_t)b * 256 + hf * 128 + col) * 1024 + n0 +
                rg * 4) = vv;
  }
}

// ---------------------------------------------------------------------------
extern "C" void kernel_launch(void* const* d_in, const int* in_sizes, int n_in,
                              void* d_out, int out_size, void* d_ws,
                              size_t ws_size, hipStream_t stream) {
  (void)in_sizes; (void)n_in; (void)out_size; (void)ws_size;
  const float* x = (const float*)d_in[0];

  half_t* ws = (half_t*)d_ws;
  half_t* qfp = ws;                    // [16][8][1024][32] f16
  half_t* kfp = ws + 4194304;          // [16][8][1024][32] f16
  half_t* vfp = ws + 8388608;          // [16][8][32][1024] f16 (permuted)
  half_t* aop = ws + 12582912;         // [16384][256] f16
  half_t* wfp = ws + 16777216;         // 8 x 16384 f16, fragment layout
  float* tabd = (float*)((char*)d_ws + 33816576);   // [8][3970][2] f32
  float* bws = (float*)((char*)d_ws + 34070656);    // [8][128] f32

  PtrArr8 wsrc, bsrc;
  const int widx[8] = {1, 3, 5, 7, 9, 11, 13, 15};
  for (int i = 0; i < 8; i++) {
    wsrc.p[i] = (const float*)d_in[widx[i]];
    bsrc.p[i] = (const float*)d_in[widx[i] + 1];
  }

  prep_all<<<144, 256, 0, stream>>>(wsrc, bsrc, wfp, bws,
                                    (const float*)d_in[18],
                                    (const float*)d_in[19],
                                    (const float*)d_in[20],
                                    (const float*)d_in[17], tabd);
  qkv_mfma<<<dim3(512, 2), 256, 0, stream>>>(x, wfp, (const float*)d_in[17],
                                             bws, qfp, kfp, vfp);
  attn_mfma<<<1024, 512, 0, stream>>>(qfp, kfp, vfp, tabd, aop);
  proj_mfma<<<dim3(512, 2), 256, 0, stream>>>(aop, wfp, bws, (float*)d_out);
}

// Round 16
// 183.945 us; speedup vs baseline: 3.8209x; 1.0242x over previous
//
#include <hip/hip_runtime.h>
#include <cmath>

// ---------------------------------------------------------------------------
// SwinV2-style window attention, f16-MFMA implementation.  Round 22.
//
// R21 crashed: proj's copy loop ran i<8 (2x out of bounds; correct count is
// 2048 float4 / 512 thr = 4) and launch_bounds(512,4) demanded 32 waves/CU
// -> 64-VGPR cap -> spills.  R22 fixes both: i<4, launch_bounds(512,2).
// Theory unchanged from R21: 64-ROW blocks for qkv+proj (same 16 waves/CU,
// W-fragment reads halved, barriers halved, prologue amortized 2x).
// attn = R20 split-K verbatim, prep = R16.
// ---------------------------------------------------------------------------

typedef _Float16 half_t;
typedef __attribute__((ext_vector_type(2))) __fp16 fp16x2;
typedef __attribute__((ext_vector_type(4))) _Float16 half4;
typedef __attribute__((ext_vector_type(8))) _Float16 half8;
typedef __attribute__((ext_vector_type(2))) float float2v;
typedef __attribute__((ext_vector_type(4))) float float4v;
typedef __attribute__((ext_vector_type(4))) unsigned int uint4v;

static __device__ __forceinline__ float4v mfma16(half8 a, half8 b, float4v c) {
  return __builtin_amdgcn_mfma_f32_16x16x32_f16(a, b, c, 0, 0, 0);
}

struct PtrArr8 { const float* p[8]; };

// ---------------------------------------------------------------------------
// prep_all: blocks 0..127 = prep_w (fp32 W -> f16 (+I), pre-fragmented
// B-layout + bias pack); blocks 128..143 = bias_mlp -> tabd[h][p] =
// {tab[p-1], tab[p]} (pair-replicated, f32, 3970 entries/h).
// ---------------------------------------------------------------------------
__global__ __launch_bounds__(256) void prep_all(
    PtrArr8 wsrc, PtrArr8 bsrc, half_t* __restrict__ wf,
    float* __restrict__ bws, const float* __restrict__ w1,
    const float* __restrict__ b1, const float* __restrict__ w2,
    const float* __restrict__ ls, float* __restrict__ tabd) {
  __shared__ float smem[1408];  // bias branch: sw1[256] sb1[128] sw2[1024]
  int blk = blockIdx.x;
  int t = threadIdx.x;
  if (blk < 128) {
    int y = blk >> 4, xx = blk & 15;
    const float* src = nullptr;
    const float* bs = nullptr;
#pragma unroll
    for (int i = 0; i < 8; i++)
      if (i == y) { src = wsrc.p[i]; bs = bsrc.p[i]; }
    int flat = (xx * 256 + t) * 4;
    float4 w = *(const float4*)(src + flat);
    int j = flat >> 7, k = flat & 127;
    if (y < 6) {
      if (k == j)     w.x += 1.0f;
      if (k + 1 == j) w.y += 1.0f;
      if (k + 2 == j) w.z += 1.0f;
      if (k + 3 == j) w.w += 1.0f;
    }
    half4 h;
    h[0] = (half_t)w.x;
    h[1] = (half_t)w.y;
    h[2] = (half_t)w.z;
    h[3] = (half_t)w.w;
    int ng = j >> 4, l = j & 15, ks = k >> 5, quad = (k >> 3) & 3, o8 = k & 7;
    *(half4*)(wf + y * 16384 + ((ng * 4 + ks) * 64 + quad * 16 + l) * 8 +
              o8) = h;
    if (xx == 0 && t < 128) bws[y * 128 + t] = bs[t];
  } else {
    float* sw1 = smem;
    float* sb1 = smem + 256;
    float* sw2 = smem + 384;
    sw1[t] = w1[t];
    if (t < 128) sb1[t] = b1[t];
    for (int i = t; i < 1024; i += 256) sw2[i] = w2[i];
    __syncthreads();
    int p = (blk - 128) * 256 + t;
    if (p >= 3969) return;
    int ph = p / 63, pw = p % 63;
    float t0 = (float)(ph - 31) * (3.2f / 31.0f);
    float t1 = (float)(pw - 31) * (3.2f / 31.0f);
    t0 = copysignf(1.0f - __expf(-fabsf(t0)), t0);
    t1 = copysignf(1.0f - __expf(-fabsf(t1)), t1);
    float acc[8];
#pragma unroll
    for (int hh = 0; hh < 8; hh++) acc[hh] = 0.0f;
    for (int j = 0; j < 128; j++) {
      float hj = fmaxf(0.0f, t0 * sw1[2 * j] + t1 * sw1[2 * j + 1] + sb1[j]);
#pragma unroll
      for (int hh = 0; hh < 8; hh++) acc[hh] += hj * sw2[hh * 128 + j];
    }
    const float L2E = 1.44269504f;
#pragma unroll
    for (int hh = 0; hh < 8; hh++) {
      float scale = __expf(fminf(ls[hh], 4.6051702f));
      float c14 = 14.0f - (scale + 16.0f) * L2E;
      float bias = 16.0f / (1.0f + __expf(-acc[hh]));
      float v = bias * L2E + c14;
      float* td = tabd + hh * 7940;  // float2[3970] per h
      td[p * 2 + 1] = v;        // tabd[h][p].y   = tab[p]
      td[p * 2 + 2] = v;        // tabd[h][p+1].x = tab[p]
      if (p == 0) td[0] = 0.0f; // tabd[h][0].x   = 0 (tab[-1])
    }
  }
}

// ---------------------------------------------------------------------------
// qkv_mfma: 3 fused linears (residual folded into W), per-head q/k norm,
// q scaled by scale*log2e.  R22: 64-ROW blocks, grid (256, 2 hf) x 512 thr
// (8 waves = 4 row strips x 2 col halves), launch_bounds(512,2).
// x staged via LDS [ch][68].  V PRE-PERMUTED; block = one full 64-key
// permutation group.
// ---------------------------------------------------------------------------
__global__ __launch_bounds__(512, 2) void qkv_mfma(
    const float* __restrict__ x, const half_t* __restrict__ wfrag,
    const float* __restrict__ lscale, const float* __restrict__ bws,
    half_t* __restrict__ qf, half_t* __restrict__ kf,
    half_t* __restrict__ vf) {
  __shared__ half_t tbuf[8704];  // x-stage [128][68] | q/k [64][136] |
                                 // v [128][68]
  int t = threadIdx.x;
  int lane = t & 63, wv = t >> 6, l = lane & 15, quad = lane >> 4;
  int rs = wv & 3, cw = wv >> 2;  // row strip (16 rows), col half
  int hf = blockIdx.y;
  int m0 = blockIdx.x * 64;
  int b = m0 >> 10, n0 = m0 & 1023;

  // stage x[rows n0..n0+63][this half's 128 ch] -> tbuf[ch][68] (coalesced)
  {
    const float* xb = x + ((size_t)b * 256 + hf * 128) * 1024 + n0;
    int ch = t >> 4, no = (t & 15) * 4;
#pragma unroll
    for (int p = 0; p < 4; p++) {
      float4 v = *(const float4*)(xb + (size_t)(p * 32 + ch) * 1024 + no);
      half4 h;
      h[0] = (half_t)v.x;
      h[1] = (half_t)v.y;
      h[2] = (half_t)v.z;
      h[3] = (half_t)v.w;
      *(half4*)(tbuf + (p * 32 + ch) * 68 + no) = h;
    }
  }
  __syncthreads();

  // A fragments: 16 rows (rs strip), this half's 128 channels, from LDS.
  half8 afr[4];
#pragma unroll
  for (int ks = 0; ks < 4; ks++) {
    half8 a;
#pragma unroll
    for (int j = 0; j < 8; j++)
      a[j] = tbuf[(ks * 32 + quad * 8 + j) * 68 + rs * 16 + l];
    afr[ks] = a;
  }
  __syncthreads();  // xs dead; tbuf reused by epilogues below

  for (int op = 0; op < 3; op++) {
    int combo = op * 2 + hf;
    const half_t* wfb = wfrag + combo * 16384;
    float4v acc[4];
#pragma unroll
    for (int ngl = 0; ngl < 4; ngl++) {
      int ng = cw * 4 + ngl;
      float4v c = {0.f, 0.f, 0.f, 0.f};
#pragma unroll
      for (int ks = 0; ks < 4; ks++) {
        half8 bfrag =
            *(const half8*)(wfb + ((ng * 4 + ks) * 64 + lane) * 8);
        c = mfma16(afr[ks], bfrag, c);
      }
      acc[ngl] = c;
    }
#pragma unroll
    for (int ngl = 0; ngl < 4; ngl++) {
      float bb = bws[combo * 128 + (cw * 4 + ngl) * 16 + l];
#pragma unroll
      for (int r2 = 0; r2 < 4; r2++) acc[ngl][r2] += bb;
    }
    if (op < 2) {
      // normalize per head: this wave's heads = hf*4 + cw*2 + {0,1}
#pragma unroll
      for (int hgl = 0; hgl < 2; hgl++) {
        float sc = 1.0f;
        if (op == 0)
          sc = __expf(fminf(lscale[hf * 4 + cw * 2 + hgl], 4.6051702f)) *
               1.44269504f;
#pragma unroll
        for (int r2 = 0; r2 < 4; r2++) {
          float ss = acc[2 * hgl][r2] * acc[2 * hgl][r2] +
                     acc[2 * hgl + 1][r2] * acc[2 * hgl + 1][r2];
          ss += __shfl_xor(ss, 1, 64);
          ss += __shfl_xor(ss, 2, 64);
          ss += __shfl_xor(ss, 4, 64);
          ss += __shfl_xor(ss, 8, 64);
          float rn = sc / fmaxf(sqrtf(ss), 1e-12f);
          acc[2 * hgl][r2] *= rn;
          acc[2 * hgl + 1][r2] *= rn;
        }
      }
      // transpose via LDS [row64][col128] stride 136 -> coalesced half8
#pragma unroll
      for (int ngl = 0; ngl < 4; ngl++)
#pragma unroll
        for (int r2 = 0; r2 < 4; r2++)
          tbuf[(rs * 16 + quad * 4 + r2) * 136 + (cw * 4 + ngl) * 16 + l] =
              (half_t)acc[ngl][r2];
      __syncthreads();
      half_t* dst = (op == 0) ? qf : kf;
#pragma unroll
      for (int i = 0; i < 2; i++) {
        int idx = t + 512 * i;
        int row = idx >> 4, colc = (idx & 15) * 8;
        half8 vv = *(const half8*)(tbuf + row * 136 + colc);
        int head = hf * 4 + (colc >> 5), d = colc & 31;
        *(half8*)(dst + (((size_t)b * 8 + head) * 1024 + n0 + row) * 32 + d) =
            vv;
      }
      __syncthreads();
    } else {
      // v: [col128][row64] stride 68 -> permuted dword to [b][h][d][n~]
#pragma unroll
      for (int ngl = 0; ngl < 4; ngl++) {
        int col = (cw * 4 + ngl) * 16 + l;
        half4 hv;
#pragma unroll
        for (int r2 = 0; r2 < 4; r2++) hv[r2] = (half_t)acc[ngl][r2];
        *(half4*)(tbuf + col * 68 + rs * 16 + quad * 4) = hv;
      }
      __syncthreads();
#pragma unroll
      for (int i = 0; i < 8; i++) {
        int idx = t + 512 * i;
        int col = idx >> 5, rp = idx & 31;
        unsigned int val = *(const unsigned int*)(tbuf + col * 68 + rp * 2);
        int head = hf * 4 + (col >> 5);
        int d = col & 31;
        // key_local = rp*2+e, bits [a1 a0 q1 q0 ks e] -> s=q*16+ks*8+a*2+e
        int npos = n0 + ((rp >> 1) & 3) * 16 + (rp & 1) * 8 +
                   ((rp >> 3) & 3) * 2;
        *(unsigned int*)((char*)vf +
                         (((((size_t)b * 8 + head) * 32 + d) * 1024) + npos) *
                             2) = val;
      }
    }
  }
}

// ---------------------------------------------------------------------------
// attn_mfma: SPLIT-K flash attention (R20, verbatim), XCD-local K/V,
// register-resident P.  grid 1024 x 512 thr (8 waves): wave (wq, wk) =
// q-strip wq*32 rows, keys kt in [wk*8, wk*8+8).  No running max ->
// partials merge by pure addition through LDS red[] after one barrier.
// ---------------------------------------------------------------------------

#define LOADK(kt)                                                           \
  {                                                                         \
    _Pragma("unroll") for (int nt = 0; nt < 4; nt++)                        \
        kfr[nt] = *(const half8*)(kbase + ((kt)*64 + nt * 16 + l) * 32 +    \
                                  quad * 8);                                \
  }

#define LOADV(kt)                                                           \
  {                                                                         \
    _Pragma("unroll") for (int ks = 0; ks < 2; ks++) {                      \
      vv0[ks] = *(const half8*)(vbase + l * 1024 + (kt)*64 + quad * 16 +    \
                                ks * 8);                                    \
      vv1[ks] = *(const half8*)(vbase + (16 + l) * 1024 + (kt)*64 +         \
                                quad * 16 + ks * 8);                        \
    }                                                                       \
  }

#define QK_PHASE(kt, S, SR)                                                 \
  {                                                                         \
    int rowb = (wq + 31 - 2 * (kt)) * 63 + cA + (S)*16;                     \
    _Pragma("unroll") for (int nt = 0; nt < 4; nt++) {                      \
      int base = rowb - (nt >> 1) * 63 - (nt & 1) * 16;                     \
      float2v p0 = sb2d[base];                                              \
      float2v p1 = sb2d[base - 2];                                          \
      float4v c;                                                            \
      c[0] = p0[1];                                                         \
      c[1] = p0[0];                                                         \
      c[2] = p1[1];                                                         \
      c[3] = p1[0];                                                         \
      SR[nt] = mfma16(kfr[nt], qfr[S], c);                                  \
    }                                                                       \
  }

#define EXP_PACK(S, SR)                                                     \
  {                                                                         \
    unsigned int w0[4], w1[4];                                              \
    _Pragma("unroll") for (int nt = 0; nt < 4; nt++) {                      \
      fp16x2 plo = __builtin_amdgcn_cvt_pkrtz(                              \
          __builtin_amdgcn_exp2f(SR[nt][0]),                                \
          __builtin_amdgcn_exp2f(SR[nt][1]));                               \
      fp16x2 phi = __builtin_amdgcn_cvt_pkrtz(                              \
          __builtin_amdgcn_exp2f(SR[nt][2]),                                \
          __builtin_amdgcn_exp2f(SR[nt][3]));                               \
      w0[nt] = __builtin_bit_cast(unsigned int, plo);                       \
      w1[nt] = __builtin_bit_cast(unsigned int, phi);                       \
    }                                                                       \
    uint4v u0 = {w0[0], w0[1], w0[2], w0[3]};                               \
    uint4v u1 = {w1[0], w1[1], w1[2], w1[3]};                               \
    pf##S[0] = __builtin_bit_cast(half8, u0);                               \
    pf##S[1] = __builtin_bit_cast(half8, u1);                               \
  }

#define PV_PHASE(S)                                                         \
  {                                                                         \
    _Pragma("unroll") for (int ks = 0; ks < 2; ks++) {                      \
      o0[S] = mfma16(pf##S[ks], vv0[ks], o0[S]);                            \
      o1[S] = mfma16(pf##S[ks], vv1[ks], o1[S]);                            \
      accl[S] = mfma16(pf##S[ks], ones, accl[S]);                           \
    }                                                                       \
  }

__global__ __launch_bounds__(512) void attn_mfma(
    const half_t* __restrict__ qf, const half_t* __restrict__ kf,
    const half_t* __restrict__ vf, const float* __restrict__ tabd,
    half_t* __restrict__ ao) {
  __shared__ float2v sb2d[2205];   // bias pairs {tab[i-1], tab[i]}, 17.6KB
  __shared__ float red[24 * 256];  // split-K partials, 24.6KB

  int id = blockIdx.x;
  int qo = id >> 7;
  int bh = id & 127;
  int h = bh & 7, b = bh >> 3;
  int t = threadIdx.x;
  int lane = t & 63, wv = t >> 6, l = lane & 15, quad = lane >> 4;
  int wq = wv & 3, wk = wv >> 2;  // q-strip, key-half
  size_t bhs = (size_t)b * 8 + h;
  const half_t* kbase = kf + bhs * 1024 * 32;
  const half_t* vbase = vf + bhs * 32 * 1024;
  int row0 = qo * 128 + wq * 32;
  int cA = l + 31 - quad * 4;
  int kt0 = wk * 8;

  half8 kfr[4], vv0[2], vv1[2], qfr[2], pf0[2], pf1[2];
  LOADK(kt0);
  LOADV(kt0);
#pragma unroll
  for (int s = 0; s < 2; s++)
    qfr[s] = *(const half8*)(qf + (bhs * 1024 + row0 + s * 16 + l) * 32 +
                             quad * 8);

  // stage bias pairs: straight coalesced b64 copy from prebuilt tabd
  {
    const float2v* td =
        (const float2v*)(tabd + (size_t)h * 7940) + qo * 252;
    for (int i = t; i < 2205; i += 512) sb2d[i] = td[i];
  }

  float4v o0[2], o1[2], accl[2];
#pragma unroll
  for (int s = 0; s < 2; s++) {
    o0[s] = (float4v){0.f, 0.f, 0.f, 0.f};
    o1[s] = (float4v){0.f, 0.f, 0.f, 0.f};
    accl[s] = (float4v){0.f, 0.f, 0.f, 0.f};
  }
  half8 ones;
#pragma unroll
  for (int j = 0; j < 8; j++) ones[j] = (half_t)1.0f;

  __syncthreads();  // bias staged

#pragma unroll
  for (int i = 0; i < 8; ++i) {
    int kt = kt0 + i;
    float4v sres[4];
    QK_PHASE(kt, 0, sres);
    EXP_PACK(0, sres);
    float4v sres2[4];
    QK_PHASE(kt, 1, sres2);
    if (i < 7) LOADK(kt + 1);  // kfr consumed by QK above
    EXP_PACK(1, sres2);
    PV_PHASE(0);
    PV_PHASE(1);
    if (i < 7) LOADV(kt + 1);  // vv consumed by PV above
  }

  // split-K merge: wk=1 publishes partials; wk=0 adds and stores.
  int rbase = wq * 64 + lane;
  if (wk == 1) {
#pragma unroll
    for (int s = 0; s < 2; s++)
#pragma unroll
      for (int r2 = 0; r2 < 4; r2++) {
        red[(s * 12 + r2) * 256 + rbase] = o0[s][r2];
        red[(s * 12 + 4 + r2) * 256 + rbase] = o1[s][r2];
        red[(s * 12 + 8 + r2) * 256 + rbase] = accl[s][r2];
      }
  }
  __syncthreads();
  if (wk == 0) {
#pragma unroll
    for (int s = 0; s < 2; s++) {
#pragma unroll
      for (int r2 = 0; r2 < 4; r2++) {
        o0[s][r2] += red[(s * 12 + r2) * 256 + rbase];
        o1[s][r2] += red[(s * 12 + 4 + r2) * 256 + rbase];
        accl[s][r2] += red[(s * 12 + 8 + r2) * 256 + rbase];
      }
    }
#pragma unroll
    for (int s = 0; s < 2; s++) {
#pragma unroll
      for (int r2 = 0; r2 < 4; r2++) {
        float linv = 1.0f / accl[s][r2];
        size_t rowaddr =
            ((size_t)b * 1024 + row0 + s * 16 + quad * 4 + r2) * 256 +
            h * 32;
        ao[rowaddr + l] = (half_t)(o0[s][r2] * linv);
        ao[rowaddr + 16 + l] = (half_t)(o1[s][r2] * linv);
      }
    }
  }
}

// ---------------------------------------------------------------------------
// proj_mfma: output projection, fp32 out [b][ch][n] via LDS transpose.
// R22: 64-ROW blocks, grid (256, 2 hf) x 512 thr, launch_bounds(512,2).
// Copy loop: 128 cols x 16 float4 = 2048 vectors / 512 thr = 4 iters.
// ---------------------------------------------------------------------------
__global__ __launch_bounds__(512, 2) void proj_mfma(
    const half_t* __restrict__ ao, const half_t* __restrict__ wfrag,
    const float* __restrict__ bws, float* __restrict__ out) {
  __shared__ float yt[8704];  // [128 ch][68] f32, 34.8KB
  int t = threadIdx.x;
  int lane = t & 63, wv = t >> 6, l = lane & 15, quad = lane >> 4;
  int rs = wv & 3, cw = wv >> 2;
  int hf = blockIdx.y;
  int m0 = blockIdx.x * 64;
  int b = m0 >> 10, n0 = m0 & 1023;

  half8 afr[4];
  const half_t* ab =
      ao + ((size_t)m0 + rs * 16 + l) * 256 + hf * 128 + quad * 8;
#pragma unroll
  for (int ks = 0; ks < 4; ks++) afr[ks] = *(const half8*)(ab + ks * 32);

  const half_t* wfb = wfrag + (6 + hf) * 16384;
#pragma unroll
  for (int ngl = 0; ngl < 4; ngl++) {
    int ng = cw * 4 + ngl;
    float4v c = {0.f, 0.f, 0.f, 0.f};
#pragma unroll
    for (int ks = 0; ks < 4; ks++) {
      half8 bfrag = *(const half8*)(wfb + ((ng * 4 + ks) * 64 + lane) * 8);
      c = mfma16(afr[ks], bfrag, c);
    }
    float bb = bws[(6 + hf) * 128 + ng * 16 + l];
#pragma unroll
    for (int r2 = 0; r2 < 4; r2++) c[r2] += bb;
    *(float4v*)(yt + (ng * 16 + l) * 68 + rs * 16 + quad * 4) = c;
  }
  __syncthreads();
#pragma unroll
  for (int i = 0; i < 4; i++) {
    int idx = t + 512 * i;
    int col = idx >> 4, rg = idx & 15;
    float4v vv = *(const float4v*)(yt + col * 68 + rg * 4);
    *(float4v*)(out + ((size_t)b * 256 + hf * 128 + col) * 1024 + n0 +
                rg * 4) = vv;
  }
}

// ---------------------------------------------------------------------------
extern "C" void kernel_launch(void* const* d_in, const int* in_sizes, int n_in,
                              void* d_out, int out_size, void* d_ws,
                              size_t ws_size, hipStream_t stream) {
  (void)in_sizes; (void)n_in; (void)out_size; (void)ws_size;
  const float* x = (const float*)d_in[0];

  half_t* ws = (half_t*)d_ws;
  half_t* qfp = ws;                    // [16][8][1024][32] f16
  half_t* kfp = ws + 4194304;          // [16][8][1024][32] f16
  half_t* vfp = ws + 8388608;          // [16][8][32][1024] f16 (permuted)
  half_t* aop = ws + 12582912;         // [16384][256] f16
  half_t* wfp = ws + 16777216;         // 8 x 16384 f16, fragment layout
  float* tabd = (float*)((char*)d_ws + 33816576);   // [8][3970][2] f32
  float* bws = (float*)((char*)d_ws + 34070656);    // [8][128] f32

  PtrArr8 wsrc, bsrc;
  const int widx[8] = {1, 3, 5, 7, 9, 11, 13, 15};
  for (int i = 0; i < 8; i++) {
    wsrc.p[i] = (const float*)d_in[widx[i]];
    bsrc.p[i] = (const float*)d_in[widx[i] + 1];
  }

  prep_all<<<144, 256, 0, stream>>>(wsrc, bsrc, wfp, bws,
                                    (const float*)d_in[18],
                                    (const float*)d_in[19],
                                    (const float*)d_in[20],
                                    (const float*)d_in[17], tabd);
  qkv_mfma<<<dim3(256, 2), 512, 0, stream>>>(x, wfp, (const float*)d_in[17],
                                             bws, qfp, kfp, vfp);
  attn_mfma<<<1024, 512, 0, stream>>>(qfp, kfp, vfp, tabd, aop);
  proj_mfma<<<dim3(256, 2), 512, 0, stream>>>(aop, wfp, bws, (float*)d_out);
}